// Round 7
// baseline (247.363 us; speedup 1.0000x reference)
//
#include <hip/hip_runtime.h>
#include <hip/hip_bf16.h>
#include <cstdint>
#include <cstddef>

#define MDIM 4096
#define NDIM 4096
#define KDIM 4096

#define BM 256
#define BN 256
#define BK 64
#define NT (KDIM / BK)   // 64 K-tiles (even)

typedef __bf16 bf16_t;
typedef bf16_t bf16x8 __attribute__((ext_vector_type(8)));
typedef float f32x4 __attribute__((ext_vector_type(4)));

#define GLDS16(gsrc, ldst)                                                   \
    __builtin_amdgcn_global_load_lds(                                        \
        (__attribute__((address_space(1))) void*)(gsrc),                     \
        (__attribute__((address_space(3))) void*)(ldst), 16, 0, 0)

#define BAR()   __builtin_amdgcn_s_barrier()
#define VM4()   asm volatile("s_waitcnt vmcnt(4)" ::: "memory")
#define VM0()   asm volatile("s_waitcnt vmcnt(0)" ::: "memory")
#define PRIO1() __builtin_amdgcn_s_setprio(1)
#define PRIO0() __builtin_amdgcn_s_setprio(0)

// Full 3-bit XOR swizzle for 128B-row tiles: byte ^= (row&7)<<4.
// Verified round 3: SQ_LDS_BANK_CONFLICT -> 0.
__device__ __forceinline__ int swz(int q) { return q ^ (((q >> 7) & 7) << 4); }

// ---------------- fp32 -> bf16 conversion pass ----------------
__global__ void cvt_f32_to_bf16(const float* __restrict__ src,
                                bf16_t* __restrict__ dst, int n) {
    int idx = (blockIdx.x * blockDim.x + threadIdx.x) * 8;
    int stride = gridDim.x * blockDim.x * 8;
    for (int i = idx; i < n; i += stride) {
        const float4* s = reinterpret_cast<const float4*>(src + i);
        float4 a = s[0];
        float4 b = s[1];
        bf16x8 o;
        o[0] = (bf16_t)a.x; o[1] = (bf16_t)a.y;
        o[2] = (bf16_t)a.z; o[3] = (bf16_t)a.w;
        o[4] = (bf16_t)b.x; o[5] = (bf16_t)b.y;
        o[6] = (bf16_t)b.z; o[7] = (bf16_t)b.w;
        *reinterpret_cast<bf16x8*>(dst + i) = o;
    }
}

// ------- 256x256 bf16 NT-GEMM: R3 skeleton + cross-phase register pipeline --
// R3 measured 4800 cyc/tile = MFMA(2368) + LDS(2304) SERIALIZED (1 WG/CU;
// each phase's ds_reads feed that phase's MFMA -> wait-all before compute).
// Fix: issue fragment reads >=1 phase before their consuming MFMA; the
// backend then emits counted lgkmcnt waits and the LDS pipe runs under the
// MFMA shadow.  Quadrants ordered (0,0)->(0,1)->(1,1)->(1,0):
//   P1: issue A0(8)+B0(4)+B1(4) reads; MFMA Q(0,0) [waits A0,B0 only]
//   P2: issue A1(8) reads;             MFMA Q(0,1) [A0,B1 issued P1]
//   P3: no reads;                      MFMA Q(1,1) [A1 issued P2]
//   P4: no reads;                      MFMA Q(1,0); VM4; BAR
// Sync/staging skeleton is R3 verbatim: 2 BAR/phase, stages P1:A1(t+1,^1)
// P2:B1(t+1,^1) P3:B0(t+2,cur) P4:A0(t+2,cur), single VM4 per tile at P4.
// WAR: staged slots B0/A0 are register-read at P1 (earlier than R3) -> safe.

// ds_read address compression: for q = row*128 + kb (kb<128, 16B-aligned),
// swz(q) = q ^ ((lrow&7)<<4)  (row&7 == lrow&7, per-lane constant), so
// frag offsets = laneBase[ko] + (const row delta)*128 -> literal offsets.

#define RD_A(dst, H, BUF) do {                                               \
  _Pragma("unroll") for (int mi = 0; mi < 4; ++mi)                           \
  _Pragma("unroll") for (int ko = 0; ko < 2; ++ko)                           \
    dst[mi][ko] = *(const bf16x8*)(ldsb + ((BUF) << 16) + aB[ko] +           \
                                   (H) * 8192 + mi * 2048);                  \
} while (0)

#define RD_B(dst, NP, BUF) do {                                              \
  _Pragma("unroll") for (int ni = 0; ni < 2; ++ni)                           \
  _Pragma("unroll") for (int ko = 0; ko < 2; ++ko)                           \
    dst[ni][ko] = *(const bf16x8*)(ldsb + ((BUF) << 16) + bB[ko] +           \
                                   (NP) * 4096 + ni * 2048);                 \
} while (0)

#define MFMA_Q(AV, BV, MH, NP) do {                                          \
  _Pragma("unroll") for (int mi = 0; mi < 4; ++mi)                           \
  _Pragma("unroll") for (int ni = 0; ni < 2; ++ni)                           \
  _Pragma("unroll") for (int ko = 0; ko < 2; ++ko)                           \
    acc[(MH)*4 + mi][(NP)*2 + ni] = __builtin_amdgcn_mfma_f32_16x16x32_bf16( \
        AV[mi][ko], BV[ni][ko], acc[(MH)*4 + mi][(NP)*2 + ni], 0, 0, 0);     \
} while (0)

#define TILE(T, BUF) do {                                                    \
    /* P1 */                                                                 \
    RD_A(a0v, 0, BUF); RD_B(b0v, 0, BUF); RD_B(b1v, 1, BUF);                 \
    if ((T) + 1 < NT) stA((T) + 1, (BUF) ^ 1, 1);                            \
    BAR();                                                                   \
    PRIO1(); MFMA_Q(a0v, b0v, 0, 0); PRIO0();                                \
    BAR();                                                                   \
    /* P2 */                                                                 \
    RD_A(a1v, 1, BUF);                                                       \
    if ((T) + 1 < NT) stB((T) + 1, (BUF) ^ 1, 1);                            \
    BAR();                                                                   \
    PRIO1(); MFMA_Q(a0v, b1v, 0, 1); PRIO0();                                \
    BAR();                                                                   \
    /* P3 */                                                                 \
    if ((T) + 2 < NT) stB((T) + 2, (BUF), 0);                                \
    BAR();                                                                   \
    PRIO1(); MFMA_Q(a1v, b1v, 1, 1); PRIO0();                                \
    BAR();                                                                   \
    /* P4 */                                                                 \
    if ((T) + 2 < NT) stA((T) + 2, (BUF), 0);                                \
    BAR();                                                                   \
    PRIO1(); MFMA_Q(a1v, b0v, 1, 0); PRIO0();                                \
    if ((T) < NT - 2) { VM4(); } else { VM0(); }                             \
    BAR();                                                                   \
} while (0)

__global__ __launch_bounds__(512, 2) void gemm256(const bf16_t* __restrict__ A,
                                                  const bf16_t* __restrict__ B,
                                                  const float* __restrict__ beta,
                                                  float* __restrict__ out) {
    extern __shared__ char ldsb[];   // 131072 bytes, dynamic

    const int tid    = threadIdx.x;
    const int wid    = tid >> 6;
    const int lane   = tid & 63;
    const int warp_m = wid >> 2;     // 0..1
    const int warp_n = wid & 3;      // 0..3
    const int lrow   = lane & 15;
    const int kgrp   = lane >> 4;

    // XCD-aware swizzle (grid = 256 = 8 XCDs x 32; bijective)
    const int bid  = blockIdx.x;
    const int sbid = (bid & 7) * 32 + (bid >> 3);
    const int brow = (sbid >> 4) * BM;
    const int bcol = (sbid & 15) * BN;

    // ---- staging precompute (verbatim R3) ----
    const int p0 = tid * 16, p1 = (tid + 512) * 16;
    const int q0 = swz(p0), q1 = swz(p1);
    const int rh0 = q0 >> 7, ce0 = (q0 & 127) >> 1;
    const int rh1 = q1 >> 7, ce1 = (q1 & 127) >> 1;

    const bf16_t* gA = A + (size_t)brow * KDIM;
    const bf16_t* gB = B + (size_t)bcol * KDIM;

    int off[2][2];
#pragma unroll
    for (int h = 0; h < 2; ++h) {
        off[h][0] = (h * 128 + rh0) * KDIM + ce0;
        off[h][1] = (h * 128 + rh1) * KDIM + ce1;
    }

    auto stA = [&](int t, int buf, int h) {
        const bf16_t* g = gA + t * BK;
        char* d = ldsb + (buf << 16) + (h << 14);
        GLDS16(g + off[h][0], d + p0);
        GLDS16(g + off[h][1], d + p1);
    };
    auto stB = [&](int t, int buf, int h) {
        const bf16_t* g = gB + t * BK;
        char* d = ldsb + (buf << 16) + ((2 + h) << 14);
        GLDS16(g + off[h][0], d + p0);
        GLDS16(g + off[h][1], d + p1);
    };

    // ---- compressed ds_read lane-bases (same addresses as R3's a_off/b_off)
    const int kx = ((lrow & 7) << 4);
    int aB[2], bB[2];
#pragma unroll
    for (int ko = 0; ko < 2; ++ko) {
        const int kb = ((ko * 64) + (kgrp * 16)) ^ kx;
        aB[ko] = (warp_m << 14) + lrow * 128 + kb;
        bB[ko] = ((2 + (warp_n >> 1)) << 14) + ((warp_n & 1) * 64 + lrow) * 128 + kb;
    }

    f32x4 acc[8][4];
#pragma unroll
    for (int i = 0; i < 8; ++i)
#pragma unroll
        for (int j = 0; j < 4; ++j)
            acc[i][j] = (f32x4){0.f, 0.f, 0.f, 0.f};

    bf16x8 a0v[4][2], a1v[4][2];   // A half 0 / half 1 fragments
    bf16x8 b0v[2][2], b1v[2][2];   // B pair 0 / pair 1 fragments

    // ---- prologue (verbatim R3): tile0 + B0(1),A0(1) staged; force tile0 --
    stA(0, 0, 0); stA(0, 0, 1); stB(0, 0, 0); stB(0, 0, 1);
    stB(1, 1, 0); stA(1, 1, 0);
    VM4();   // tile0's 8 loads retired; B0(1),A0(1) may fly
    BAR();   // publish tile0

    for (int t = 0; t < NT; t += 2) {
        TILE(t, 0);
        TILE(t + 1, 1);
    }

    // ---- epilogue: relu(1 - beta + acc) ----
    const float bias = 1.0f - beta[0];
    float* outp = out + (size_t)(brow + warp_m * 128) * NDIM + bcol + warp_n * 64;
#pragma unroll
    for (int mi = 0; mi < 8; ++mi)
#pragma unroll
        for (int ni = 0; ni < 4; ++ni)
#pragma unroll
            for (int j = 0; j < 4; ++j) {
                const int r = mi * 16 + kgrp * 4 + j;   // C/D: row=(lane>>4)*4+reg
                const int c = ni * 16 + lrow;           //      col=lane&15
                outp[(size_t)r * NDIM + c] = fmaxf(acc[mi][ni][j] + bias, 0.0f);
            }
}

// ---------------- fp32 fallback (only if ws too small) ----------------
__global__ void gemm_f32_fallback(const float* __restrict__ A,
                                  const float* __restrict__ B,
                                  const float* __restrict__ beta,
                                  float* __restrict__ out) {
    __shared__ float sA[16][17];
    __shared__ float sB[16][17];
    const int tx = threadIdx.x, ty = threadIdx.y;
    const int m = blockIdx.y * 16 + ty;
    const int n = blockIdx.x * 16 + tx;
    float acc = 0.f;
    for (int k0 = 0; k0 < KDIM; k0 += 16) {
        sA[ty][tx] = A[(size_t)m * KDIM + k0 + tx];
        sB[ty][tx] = B[(size_t)(blockIdx.x * 16 + ty) * KDIM + k0 + tx];
        __syncthreads();
#pragma unroll
        for (int k = 0; k < 16; ++k)
            acc += sA[ty][k] * sB[tx][k];
        __syncthreads();
    }
    float v = acc + 1.0f - beta[0];
    out[(size_t)m * NDIM + n] = fmaxf(v, 0.f);
}

extern "C" void kernel_launch(void* const* d_in, const int* in_sizes, int n_in,
                              void* d_out, int out_size, void* d_ws, size_t ws_size,
                              hipStream_t stream) {
    const float* x    = (const float*)d_in[0];
    const float* w    = (const float*)d_in[1];
    const float* beta = (const float*)d_in[2];
    float* out        = (float*)d_out;

    const size_t nelem = (size_t)MDIM * (size_t)KDIM;   // per matrix
    const size_t need  = 2 * nelem * sizeof(bf16_t);    // 64 MB

    if (ws_size >= need) {
        bf16_t* xb = (bf16_t*)d_ws;
        bf16_t* wb = xb + nelem;
        hipFuncSetAttribute((const void*)gemm256,
                            hipFuncAttributeMaxDynamicSharedMemorySize, 131072);
        cvt_f32_to_bf16<<<2048, 256, 0, stream>>>(x, xb, (int)nelem);
        cvt_f32_to_bf16<<<2048, 256, 0, stream>>>(w, wb, (int)nelem);
        gemm256<<<256, 512, 131072, stream>>>(xb, wb, beta, out);
    } else {
        dim3 grid(NDIM / 16, MDIM / 16);
        gemm_f32_fallback<<<grid, dim3(16, 16), 0, stream>>>(x, w, beta, out);
    }
}

// Round 8
// 174.669 us; speedup vs baseline: 1.4162x; 1.4162x over previous
//
#include <hip/hip_runtime.h>
#include <hip/hip_bf16.h>
#include <cstdint>
#include <cstddef>

#define MDIM 4096
#define NDIM 4096
#define KDIM 4096

#define BM 256
#define BN 256
#define BK 64
#define NT (KDIM / BK)   // 64 K-tiles (even)

typedef __bf16 bf16_t;
typedef bf16_t bf16x8 __attribute__((ext_vector_type(8)));
typedef float f32x4 __attribute__((ext_vector_type(4)));

#define GLDS16(gsrc, ldst)                                                   \
    __builtin_amdgcn_global_load_lds(                                        \
        (__attribute__((address_space(1))) void*)(gsrc),                     \
        (__attribute__((address_space(3))) void*)(ldst), 16, 0, 0)

#define BAR()   __builtin_amdgcn_s_barrier()
#define VM4()   asm volatile("s_waitcnt vmcnt(4)" ::: "memory")
#define VM0()   asm volatile("s_waitcnt vmcnt(0)" ::: "memory")
#define PRIO1() __builtin_amdgcn_s_setprio(1)
#define PRIO0() __builtin_amdgcn_s_setprio(0)

// Full 3-bit XOR swizzle for 128B-row tiles: byte ^= (row&7)<<4.
// Verified round 3: SQ_LDS_BANK_CONFLICT -> 0.
__device__ __forceinline__ int swz(int q) { return q ^ (((q >> 7) & 7) << 4); }

// ---------------- fp32 -> bf16 conversion pass ----------------
__global__ void cvt_f32_to_bf16(const float* __restrict__ src,
                                bf16_t* __restrict__ dst, int n) {
    int idx = (blockIdx.x * blockDim.x + threadIdx.x) * 8;
    int stride = gridDim.x * blockDim.x * 8;
    for (int i = idx; i < n; i += stride) {
        const float4* s = reinterpret_cast<const float4*>(src + i);
        float4 a = s[0];
        float4 b = s[1];
        bf16x8 o;
        o[0] = (bf16_t)a.x; o[1] = (bf16_t)a.y;
        o[2] = (bf16_t)a.z; o[3] = (bf16_t)a.w;
        o[4] = (bf16_t)b.x; o[5] = (bf16_t)b.y;
        o[6] = (bf16_t)b.z; o[7] = (bf16_t)b.w;
        *reinterpret_cast<bf16x8*>(dst + i) = o;
    }
}

// --------- 256x256 bf16 NT-GEMM: R3 schedule, compiler-counted lgkm --------
// R3 (128us) serialized LDS(2304cyc) + MFMA(2368cyc) per tile because the
// explicit lgkmcnt(0) made every wave wait for its ENTIRE read burst before
// any MFMA (all waves' reads interleave in the LDS queue -> wait-own-all ==
// wait-all).  Fix: NO asm lgkm wait -- MFMA operands are SSA dataflow, so the
// backend emits counted lgkmcnt(N) per first use and the LDS queue drains
// under the MFMA shadow.  One barrier per phase (at phase end).
//   P1: read A0(8)+B01(4); stage A1(t+1,^1); MFMA Q(0,0) [consumes P1 reads]
//   P2: read B23(4);       stage B1(t+1,^1); MFMA Q(0,1)
//   P3: read A1(8);        stage B0(t+2,buf); MFMA Q(1,0)
//   P4:                    stage A0(t+2,buf); MFMA Q(1,1); VM4; BAR
// WAR: each staged slot's last readers are >=2 phase-end barriers before the
// stage issue, and "MFMA consumed value => ds_read completed" (HW waitcnt
// before register use).  RAW: vmcnt(4) at P4 forces exactly tile t+1's 8
// loads (12 outstanding -> 4) before the publishing BAR -- R3's algebra.

#define LOAD_A_HALF(MH, BUF) do {                                            \
  _Pragma("unroll") for (int mi = 0; mi < 4; ++mi)                           \
  _Pragma("unroll") for (int ko = 0; ko < 2; ++ko)                           \
    av[mi][ko] = *(const bf16x8*)(ldsb + ((BUF) << 16) + a_off[(MH)*4 + mi][ko]); \
} while (0)

#define LOAD_B_PAIR(NH, BUF) do {                                            \
  _Pragma("unroll") for (int ni = 0; ni < 2; ++ni)                           \
  _Pragma("unroll") for (int ko = 0; ko < 2; ++ko)                           \
    bv[(NH)*2 + ni][ko] = *(const bf16x8*)(ldsb + ((BUF) << 16) + b_off[(NH)*2 + ni][ko]); \
} while (0)

#define MFMA_QUAD(MH, NH) do {                                               \
  _Pragma("unroll") for (int mi = 0; mi < 4; ++mi)                           \
  _Pragma("unroll") for (int ni = 0; ni < 2; ++ni)                           \
  _Pragma("unroll") for (int ko = 0; ko < 2; ++ko)                           \
    acc[(MH)*4 + mi][(NH)*2 + ni] = __builtin_amdgcn_mfma_f32_16x16x32_bf16( \
        av[mi][ko], bv[(NH)*2 + ni][ko], acc[(MH)*4 + mi][(NH)*2 + ni], 0, 0, 0); \
} while (0)

#define TILE(T, BUF) do {                                                    \
    /* P1 */                                                                 \
    LOAD_A_HALF(0, BUF); LOAD_B_PAIR(0, BUF);                                \
    if ((T) + 1 < NT) stA((T) + 1, (BUF) ^ 1, 1);                            \
    PRIO1(); MFMA_QUAD(0, 0); PRIO0();                                       \
    BAR();                                                                   \
    /* P2 */                                                                 \
    LOAD_B_PAIR(1, BUF);                                                     \
    if ((T) + 1 < NT) stB((T) + 1, (BUF) ^ 1, 1);                            \
    PRIO1(); MFMA_QUAD(0, 1); PRIO0();                                       \
    BAR();                                                                   \
    /* P3 */                                                                 \
    LOAD_A_HALF(1, BUF);                                                     \
    if ((T) + 2 < NT) stB((T) + 2, (BUF), 0);                                \
    PRIO1(); MFMA_QUAD(1, 0); PRIO0();                                       \
    BAR();                                                                   \
    /* P4 */                                                                 \
    if ((T) + 2 < NT) stA((T) + 2, (BUF), 0);                                \
    PRIO1(); MFMA_QUAD(1, 1); PRIO0();                                       \
    if ((T) < NT - 2) { VM4(); } else { VM0(); }                             \
    BAR();                                                                   \
} while (0)

__global__ __launch_bounds__(512, 2) void gemm256(const bf16_t* __restrict__ A,
                                                  const bf16_t* __restrict__ B,
                                                  const float* __restrict__ beta,
                                                  float* __restrict__ out) {
    extern __shared__ char ldsb[];   // 131072 bytes, dynamic

    const int tid    = threadIdx.x;
    const int wid    = tid >> 6;
    const int lane   = tid & 63;
    const int warp_m = wid >> 2;     // 0..1
    const int warp_n = wid & 3;      // 0..3
    const int lrow   = lane & 15;
    const int kgrp   = lane >> 4;

    // XCD-aware swizzle (grid = 256 = 8 XCDs x 32; bijective)
    const int bid  = blockIdx.x;
    const int sbid = (bid & 7) * 32 + (bid >> 3);
    const int brow = (sbid >> 4) * BM;
    const int bcol = (sbid & 15) * BN;

    // ---- staging precompute (verbatim R3) ----
    const int p0 = tid * 16, p1 = (tid + 512) * 16;
    const int q0 = swz(p0), q1 = swz(p1);
    const int rh0 = q0 >> 7, ce0 = (q0 & 127) >> 1;
    const int rh1 = q1 >> 7, ce1 = (q1 & 127) >> 1;

    const bf16_t* gA = A + (size_t)brow * KDIM;
    const bf16_t* gB = B + (size_t)bcol * KDIM;

    int off[2][2];
#pragma unroll
    for (int h = 0; h < 2; ++h) {
        off[h][0] = (h * 128 + rh0) * KDIM + ce0;
        off[h][1] = (h * 128 + rh1) * KDIM + ce1;
    }

    auto stA = [&](int t, int buf, int h) {
        const bf16_t* g = gA + t * BK;
        char* d = ldsb + (buf << 16) + (h << 14);
        GLDS16(g + off[h][0], d + p0);
        GLDS16(g + off[h][1], d + p1);
    };
    auto stB = [&](int t, int buf, int h) {
        const bf16_t* g = gB + t * BK;
        char* d = ldsb + (buf << 16) + ((2 + h) << 14);
        GLDS16(g + off[h][0], d + p0);
        GLDS16(g + off[h][1], d + p1);
    };

    // ---- ds_read offsets (swizzled), constant-indexed only (verbatim R3) --
    int a_off[8][2];
#pragma unroll
    for (int mi = 0; mi < 8; ++mi)
#pragma unroll
        for (int ko = 0; ko < 2; ++ko)
            a_off[mi][ko] = (warp_m << 14) +
                swz((mi * 16 + lrow) * 128 + (ko * 32 + kgrp * 8) * 2);
    int b_off[4][2];
#pragma unroll
    for (int ni = 0; ni < 4; ++ni)
#pragma unroll
        for (int ko = 0; ko < 2; ++ko)
            b_off[ni][ko] = ((2 + (warp_n >> 1)) << 14) +
                swz(((warp_n & 1) * 64 + ni * 16 + lrow) * 128 + (ko * 32 + kgrp * 8) * 2);

    f32x4 acc[8][4];
#pragma unroll
    for (int i = 0; i < 8; ++i)
#pragma unroll
        for (int j = 0; j < 4; ++j)
            acc[i][j] = (f32x4){0.f, 0.f, 0.f, 0.f};

    bf16x8 av[4][2];
    bf16x8 bv[4][2];

    // ---- prologue (verbatim R3): tile0 + B0(1),A0(1) staged; force tile0 --
    stA(0, 0, 0); stA(0, 0, 1); stB(0, 0, 0); stB(0, 0, 1);
    stB(1, 1, 0); stA(1, 1, 0);
    VM4();   // tile0's 8 loads retired; B0(1),A0(1) may fly
    BAR();   // publish tile0

    for (int t = 0; t < NT; t += 2) {
        TILE(t, 0);
        TILE(t + 1, 1);
    }

    // ---- epilogue: relu(1 - beta + acc) ----
    const float bias = 1.0f - beta[0];
    float* outp = out + (size_t)(brow + warp_m * 128) * NDIM + bcol + warp_n * 64;
#pragma unroll
    for (int mi = 0; mi < 8; ++mi)
#pragma unroll
        for (int ni = 0; ni < 4; ++ni)
#pragma unroll
            for (int j = 0; j < 4; ++j) {
                const int r = mi * 16 + kgrp * 4 + j;   // C/D: row=(lane>>4)*4+reg
                const int c = ni * 16 + lrow;           //      col=lane&15
                outp[(size_t)r * NDIM + c] = fmaxf(acc[mi][ni][j] + bias, 0.0f);
            }
}

// ---------------- fp32 fallback (only if ws too small) ----------------
__global__ void gemm_f32_fallback(const float* __restrict__ A,
                                  const float* __restrict__ B,
                                  const float* __restrict__ beta,
                                  float* __restrict__ out) {
    __shared__ float sA[16][17];
    __shared__ float sB[16][17];
    const int tx = threadIdx.x, ty = threadIdx.y;
    const int m = blockIdx.y * 16 + ty;
    const int n = blockIdx.x * 16 + tx;
    float acc = 0.f;
    for (int k0 = 0; k0 < KDIM; k0 += 16) {
        sA[ty][tx] = A[(size_t)m * KDIM + k0 + tx];
        sB[ty][tx] = B[(size_t)(blockIdx.x * 16 + ty) * KDIM + k0 + tx];
        __syncthreads();
#pragma unroll
        for (int k = 0; k < 16; ++k)
            acc += sA[ty][k] * sB[tx][k];
        __syncthreads();
    }
    float v = acc + 1.0f - beta[0];
    out[(size_t)m * NDIM + n] = fmaxf(v, 0.f);
}

extern "C" void kernel_launch(void* const* d_in, const int* in_sizes, int n_in,
                              void* d_out, int out_size, void* d_ws, size_t ws_size,
                              hipStream_t stream) {
    const float* x    = (const float*)d_in[0];
    const float* w    = (const float*)d_in[1];
    const float* beta = (const float*)d_in[2];
    float* out        = (float*)d_out;

    const size_t nelem = (size_t)MDIM * (size_t)KDIM;   // per matrix
    const size_t need  = 2 * nelem * sizeof(bf16_t);    // 64 MB

    if (ws_size >= need) {
        bf16_t* xb = (bf16_t*)d_ws;
        bf16_t* wb = xb + nelem;
        hipFuncSetAttribute((const void*)gemm256,
                            hipFuncAttributeMaxDynamicSharedMemorySize, 131072);
        cvt_f32_to_bf16<<<2048, 256, 0, stream>>>(x, xb, (int)nelem);
        cvt_f32_to_bf16<<<2048, 256, 0, stream>>>(w, wb, (int)nelem);
        gemm256<<<256, 512, 131072, stream>>>(xb, wb, beta, out);
    } else {
        dim3 grid(NDIM / 16, MDIM / 16);
        gemm_f32_fallback<<<grid, dim3(16, 16), 0, stream>>>(x, w, beta, out);
    }
}